// Round 1
// baseline (286.632 us; speedup 1.0000x reference)
//
#include <hip/hip_runtime.h>

#define NSEQ 4096
#define BATCH 2
#define ROWS (BATCH * NSEQ)   // 8192
#define NH 8
#define DHD 32

typedef __attribute__((ext_vector_type(8))) short bf16x8;
typedef __attribute__((ext_vector_type(4))) float f32x4;

static __device__ __forceinline__ ushort f2bf(float f) {
    union { float f; uint u; } v; v.f = f;
    uint u = v.u;
    uint r = (u + 0x7fffu + ((u >> 16) & 1u)) >> 16;   // RTNE
    return (ushort)r;
}

// ---------------- prep: x fp32 -> bf16 ----------------
__global__ __launch_bounds__(256) void k_convert_x(const float* __restrict__ x,
                                                   ushort* __restrict__ xb) {
    int i = (blockIdx.x * 256 + threadIdx.x) * 4;   // total 2097152 elems
    float4 v = *(const float4*)(x + i);
    ushort4 o;
    o.x = f2bf(v.x); o.y = f2bf(v.y); o.z = f2bf(v.z); o.w = f2bf(v.w);
    *(ushort4*)(xb + i) = o;
}

// ---------------- prep: W [K=256][ncols] fp32 -> Wt [ncols][256] bf16 ----------------
__global__ __launch_bounds__(256) void k_transpose_w(const float* __restrict__ w,
                                                     ushort* __restrict__ wt, int ncols) {
    int n = blockIdx.x * 256 + threadIdx.x;
    int k = blockIdx.y;   // 0..255
    wt[n * 256 + k] = f2bf(w[k * ncols + n]);
}

// ---------------- QKV GEMM: [8192x256]bf16 @ Wt[768][256] + bias ----------------
// writes: qk [8192][512] (cols 0..255 = Q*(1/16), 256..511 = K), vT [16][32][4096]
__global__ __launch_bounds__(256) void k_qkv(const ushort* __restrict__ xb,
                                             const ushort* __restrict__ wt,
                                             const float* __restrict__ bias,
                                             ushort* __restrict__ qk,
                                             ushort* __restrict__ vT) {
    int w = threadIdx.x >> 6, lane = threadIdx.x & 63;
    int lhi = lane >> 4, llo = lane & 15;
    int row0 = blockIdx.x * 64 + w * 16;
    int n0 = blockIdx.y * 64;

    f32x4 acc[4] = {};
#pragma unroll
    for (int ks = 0; ks < 8; ++ks) {
        int k0 = ks * 32 + lhi * 8;
        bf16x8 a = *(const bf16x8*)(xb + (row0 + llo) * 256 + k0);
#pragma unroll
        for (int fn = 0; fn < 4; ++fn) {
            bf16x8 b = *(const bf16x8*)(wt + (n0 + fn * 16 + llo) * 256 + k0);
            acc[fn] = __builtin_amdgcn_mfma_f32_16x16x32_bf16(a, b, acc[fn], 0, 0, 0);
        }
    }
#pragma unroll
    for (int fn = 0; fn < 4; ++fn) {
        int cg = n0 + fn * 16 + llo;
        int three = cg >> 8, rem = cg & 255;
        float bv = bias[cg];
#pragma unroll
        for (int r = 0; r < 4; ++r) {
            int row = row0 + lhi * 4 + r;
            float v = acc[fn][r] + bv;
            if (three == 0) {
                qk[row * 512 + rem] = f2bf(v * 0.0625f);   // pre-scale Q by C^-0.5 = 1/16
            } else if (three == 1) {
                qk[row * 512 + 256 + rem] = f2bf(v);
            } else {
                int b = row >> 12, n = row & 4095;
                int h = rem >> 5, dh = rem & 31;
                vT[((b * NH + h) * DHD + dh) * NSEQ + n] = f2bf(v);
            }
        }
    }
}

// ---------------- flash attention: 1 wave = 16 q-rows, KV tiles of 64 ----------------
__global__ __launch_bounds__(256) void k_attn(const ushort* __restrict__ qk,
                                              const ushort* __restrict__ vT,
                                              ushort* __restrict__ attn_out) {
    __shared__ __align__(16) ushort p_lds[4][1024];   // per-wave 16x64 bf16 P tile (swizzled)
    int w = threadIdx.x >> 6, lane = threadIdx.x & 63;
    int lhi = lane >> 4, llo = lane & 15;
    int wid = blockIdx.x * 4 + w;          // 0..4095
    int bh = wid >> 8;                     // 0..15 (b*8+h)
    int qt = wid & 255;
    int b = bh >> 3, h = bh & 7;
    int q0 = qt * 16;

    const ushort* qbase = qk + (size_t)(b * NSEQ) * 512 + h * DHD;
    const ushort* kbase = qbase + 256;
    const ushort* vbase = vT + (size_t)bh * DHD * NSEQ;

    bf16x8 qf = *(const bf16x8*)(qbase + (q0 + llo) * 512 + lhi * 8);
    f32x4 acc0 = {}, acc1 = {};
    float mrun = -INFINITY, lrun = 0.f;
    char* pl = (char*)&p_lds[w][0];
    const float L2E = 1.4426950408889634f;
    const f32x4 zf = {0.f, 0.f, 0.f, 0.f};
    int swz = (llo & 7) << 4;

    for (int kv = 0; kv < NSEQ; kv += 64) {
        // S^T tile: mfma(K, Q) -> lane holds S[qrow=llo][key=st*16+lhi*4+r]
        f32x4 sf[4];
#pragma unroll
        for (int st = 0; st < 4; ++st) {
            bf16x8 kf = *(const bf16x8*)(kbase + (kv + st * 16 + llo) * 512 + lhi * 8);
            sf[st] = __builtin_amdgcn_mfma_f32_16x16x32_bf16(kf, qf, zf, 0, 0, 0);
        }
        // row max over 16 per-lane values + 2 xor-shuffles
        float tm = sf[0][0];
#pragma unroll
        for (int st = 0; st < 4; ++st)
#pragma unroll
            for (int r = 0; r < 4; ++r) tm = fmaxf(tm, sf[st][r]);
        tm = fmaxf(tm, __shfl_xor(tm, 16));
        tm = fmaxf(tm, __shfl_xor(tm, 32));
        float mnew = fmaxf(mrun, tm);
        float corr = __builtin_amdgcn_exp2f((mrun - mnew) * L2E);

        float psum = 0.f;
#pragma unroll
        for (int st = 0; st < 4; ++st) {
            float p0 = __builtin_amdgcn_exp2f((sf[st][0] - mnew) * L2E);
            float p1 = __builtin_amdgcn_exp2f((sf[st][1] - mnew) * L2E);
            float p2 = __builtin_amdgcn_exp2f((sf[st][2] - mnew) * L2E);
            float p3 = __builtin_amdgcn_exp2f((sf[st][3] - mnew) * L2E);
            psum += (p0 + p1) + (p2 + p3);
            uint2 pk;
            pk.x = (uint)f2bf(p0) | ((uint)f2bf(p1) << 16);
            pk.y = (uint)f2bf(p2) | ((uint)f2bf(p3) << 16);
            int ub = st * 32 + lhi * 8;                  // byte offset within row
            *(uint2*)(pl + llo * 128 + (ub ^ swz)) = pk; // swizzled write
        }
        psum += __shfl_xor(psum, 16);
        psum += __shfl_xor(psum, 32);
        lrun = lrun * corr + psum;
        mrun = mnew;
        // rescale accumulator rows (acc row = lhi*4+r lives at source lane lhi*4+r)
#pragma unroll
        for (int r = 0; r < 4; ++r) {
            float fc = __shfl(corr, lhi * 4 + r);
            acc0[r] *= fc; acc1[r] *= fc;
        }
        // PV: A = P[16q x 64k] from LDS, B = V^T rows (contiguous in keys)
#pragma unroll
        for (int kt = 0; kt < 2; ++kt) {
            int ub = kt * 64 + lhi * 16;
            bf16x8 pf = *(const bf16x8*)(pl + llo * 128 + (ub ^ swz));
            bf16x8 v0 = *(const bf16x8*)(vbase + llo * NSEQ + kv + kt * 32 + lhi * 8);
            bf16x8 v1 = *(const bf16x8*)(vbase + (llo + 16) * NSEQ + kv + kt * 32 + lhi * 8);
            acc0 = __builtin_amdgcn_mfma_f32_16x16x32_bf16(pf, v0, acc0, 0, 0, 0);
            acc1 = __builtin_amdgcn_mfma_f32_16x16x32_bf16(pf, v1, acc1, 0, 0, 0);
        }
    }
#pragma unroll
    for (int r = 0; r < 4; ++r) {
        float li = 1.f / __shfl(lrun, lhi * 4 + r);
        int row = q0 + lhi * 4 + r;
        size_t orow = ((size_t)(b * NSEQ) + row) * 256 + h * DHD;
        attn_out[orow + llo] = f2bf(acc0[r] * li);
        attn_out[orow + 16 + llo] = f2bf(acc1[r] * li);
    }
}

// ---------------- proj GEMM: [8192x256]bf16 @ Wt[256][256] + bias -> fp32 ----------------
__global__ __launch_bounds__(256) void k_proj(const ushort* __restrict__ aout,
                                              const ushort* __restrict__ wt,
                                              const float* __restrict__ bias,
                                              float* __restrict__ out) {
    int w = threadIdx.x >> 6, lane = threadIdx.x & 63;
    int lhi = lane >> 4, llo = lane & 15;
    int row0 = blockIdx.x * 64 + w * 16;
    int n0 = blockIdx.y * 64;

    f32x4 acc[4] = {};
#pragma unroll
    for (int ks = 0; ks < 8; ++ks) {
        int k0 = ks * 32 + lhi * 8;
        bf16x8 a = *(const bf16x8*)(aout + (row0 + llo) * 256 + k0);
#pragma unroll
        for (int fn = 0; fn < 4; ++fn) {
            bf16x8 b = *(const bf16x8*)(wt + (n0 + fn * 16 + llo) * 256 + k0);
            acc[fn] = __builtin_amdgcn_mfma_f32_16x16x32_bf16(a, b, acc[fn], 0, 0, 0);
        }
    }
#pragma unroll
    for (int fn = 0; fn < 4; ++fn) {
        int cg = n0 + fn * 16 + llo;
        float bv = bias[cg];
#pragma unroll
        for (int r = 0; r < 4; ++r) {
            int row = row0 + lhi * 4 + r;
            out[(size_t)row * 256 + cg] = acc[fn][r] + bv;
        }
    }
}

extern "C" void kernel_launch(void* const* d_in, const int* in_sizes, int n_in,
                              void* d_out, int out_size, void* d_ws, size_t ws_size,
                              hipStream_t stream) {
    const float* x     = (const float*)d_in[0];
    const float* Wqkv  = (const float*)d_in[1];
    const float* bqkv  = (const float*)d_in[2];
    const float* Wproj = (const float*)d_in[3];
    const float* bproj = (const float*)d_in[4];
    float* out = (float*)d_out;

    char* ws = (char*)d_ws;
    ushort* xb     = (ushort*)(ws);                 // 8192*256*2   = 4,194,304
    ushort* wqkvT  = (ushort*)(ws + 4194304);       // 768*256*2    =   393,216
    ushort* wprojT = (ushort*)(ws + 4587520);       // 256*256*2    =   131,072
    ushort* qkbuf  = (ushort*)(ws + 4718592);       // 8192*512*2   = 8,388,608
    ushort* vT     = (ushort*)(ws + 13107200);      // 16*32*4096*2 = 4,194,304
    ushort* aoutb  = (ushort*)(ws + 17301504);      // 8192*256*2   = 4,194,304
    // total ws use: 21,495,808 bytes

    k_convert_x<<<2048, 256, 0, stream>>>(x, xb);
    k_transpose_w<<<dim3(3, 256), 256, 0, stream>>>(Wqkv, wqkvT, 768);
    k_transpose_w<<<dim3(1, 256), 256, 0, stream>>>(Wproj, wprojT, 256);
    k_qkv<<<dim3(128, 12), 256, 0, stream>>>(xb, wqkvT, bqkv, qkbuf, vT);
    k_attn<<<1024, 256, 0, stream>>>(qkbuf, vT, aoutb);
    k_proj<<<dim3(128, 4), 256, 0, stream>>>(aoutb, wprojT, bproj, out);
}